// Round 6
// baseline (873.661 us; speedup 1.0000x reference)
//
#include <hip/hip_runtime.h>

constexpr int N_NODES = 50000;
constexpr int N_EDGES = 800000;
constexpr int ND  = 32;
constexpr int ED  = 16;
constexpr int HID = 96;
constexpr int NLAYER = 3;
constexpr int NMAX = 48;    // node-slot count per 512-edge block (span ~33 avg)
constexpr int BLKE = 512;   // edges per block (4 waves x 128)

typedef unsigned short ushort_t;
typedef unsigned int uint_t;
typedef __attribute__((ext_vector_type(8))) short bf16x8;
typedef __attribute__((ext_vector_type(4))) float f32x4;

__device__ __forceinline__ float bf2f(ushort_t u) {
    union { float f; uint_t ui; } c; c.ui = ((uint_t)u) << 16; return c.f;
}
__device__ __forceinline__ ushort_t f2bf(float f) {
    uint_t u = __float_as_uint(f);
    return (ushort_t)((u + 0x7FFFu + ((u >> 16) & 1u)) >> 16);  // RNE
}

// ---------------- CSR build (by dst), once per call ----------------
__global__ void k_rank(const int* __restrict__ dst, int* __restrict__ cnt,
                       int* __restrict__ rank) {
    int e = blockIdx.x * 256 + threadIdx.x;
    if (e >= N_EDGES) return;
    rank[e] = atomicAdd(&cnt[dst[e]], 1);
}

__global__ void k_scan_block(const int* __restrict__ deg, int* __restrict__ rowptr,
                             int* __restrict__ bsum) {
    __shared__ int s[256];
    int i = blockIdx.x * 256 + threadIdx.x;
    int v = (i < N_NODES) ? deg[i] : 0;
    s[threadIdx.x] = v;
    __syncthreads();
    for (int off = 1; off < 256; off <<= 1) {
        int t = (threadIdx.x >= off) ? s[threadIdx.x - off] : 0;
        __syncthreads();
        s[threadIdx.x] += t;
        __syncthreads();
    }
    if (i < N_NODES) rowptr[i] = s[threadIdx.x] - v;
    if (threadIdx.x == 255) bsum[blockIdx.x] = s[255];
}

__global__ void k_scan_bsum(int* __restrict__ bsum, int nb) {
    __shared__ int s[256];
    int t = threadIdx.x;
    int v = (t < nb) ? bsum[t] : 0;
    s[t] = v;
    __syncthreads();
    for (int off = 1; off < 256; off <<= 1) {
        int tv = (t >= off) ? s[t - off] : 0;
        __syncthreads();
        s[t] += tv;
        __syncthreads();
    }
    if (t < nb) bsum[t] = s[t] - v;
}

__global__ void k_scan_add(int* __restrict__ rowptr, const int* __restrict__ bsum) {
    int i = blockIdx.x * 256 + threadIdx.x;
    if (i < N_NODES) rowptr[i] += bsum[blockIdx.x];
    if (i == 0) rowptr[N_NODES] = N_EDGES;
}

__global__ void k_place(const int* __restrict__ src, const int* __restrict__ dst,
                        const int* __restrict__ rank, const int* __restrict__ rowptr,
                        int2* __restrict__ csre) {
    int e = blockIdx.x * 256 + threadIdx.x;
    if (e >= N_EDGES) return;
    int p = rowptr[dst[e]] + rank[e];
    csre[p] = make_int2(src[e], e);
}

// ea written in STRIP-TRANSPOSED order: within each 128-edge chunk, CSR
// position p goes to slot (p%8)*16 + (p/8)%16, so k_evagg's strip lanes
// (lane col owns edges col*8..col*8+7) read batch b as a contiguous 512B
// wave access instead of 32B-of-64B strided (saves ~25MB over-fetch).
__global__ void k_gather(const int2* __restrict__ csre, const int* __restrict__ dstA,
                         const float* __restrict__ eattr, int* __restrict__ srcs,
                         int* __restrict__ pdst, ushort_t* __restrict__ ea) {
    int p = blockIdx.x * 256 + threadIdx.x;
    if (p >= N_EDGES) return;
    int2 se = csre[p];
    int e = se.y;
    srcs[p] = se.x;
    pdst[p] = dstA[e];
    const float4* er = (const float4*)(eattr + (size_t)e * ED);
    float4 v0 = er[0], v1 = er[1], v2 = er[2], v3 = er[3];
    uint4 w0, w1;
    w0.x = (uint_t)f2bf(v0.x) | ((uint_t)f2bf(v0.y) << 16);
    w0.y = (uint_t)f2bf(v0.z) | ((uint_t)f2bf(v0.w) << 16);
    w0.z = (uint_t)f2bf(v1.x) | ((uint_t)f2bf(v1.y) << 16);
    w0.w = (uint_t)f2bf(v1.z) | ((uint_t)f2bf(v1.w) << 16);
    w1.x = (uint_t)f2bf(v2.x) | ((uint_t)f2bf(v2.y) << 16);
    w1.y = (uint_t)f2bf(v2.z) | ((uint_t)f2bf(v2.w) << 16);
    w1.z = (uint_t)f2bf(v3.x) | ((uint_t)f2bf(v3.y) << 16);
    w1.w = (uint_t)f2bf(v3.z) | ((uint_t)f2bf(v3.w) << 16);
    int slot = (p & ~127) | (((p & 7) << 4) | ((p >> 3) & 15));
    uint4* ew = (uint4*)(ea + (size_t)slot * ED);
    ew[0] = w0;
    ew[1] = w1;
}

// ---------------- proj: h = x @ proj_w + proj_b  (K=32) ----------------
__global__ __launch_bounds__(192) void k_proj(const float* __restrict__ x,
                                              const float* __restrict__ pw,
                                              const float* __restrict__ pb,
                                              float* __restrict__ h) {
    int t = threadIdx.x;
    int c = t % 96, half = t / 96;
    float wreg[ND];
#pragma unroll
    for (int k = 0; k < ND; k++) wreg[k] = pw[k * HID + c];
    float b = pb[c];
    int n0 = blockIdx.x * 16 + half * 8;
    for (int i = 0; i < 8; i += 2) {
        int na = n0 + i, nb = na + 1;
        const float4* xa = (const float4*)(x + (size_t)na * ND);
        const float4* xb = (const float4*)(x + (size_t)nb * ND);
        float accA = b, accB = b;
#pragma unroll
        for (int k4 = 0; k4 < ND / 4; k4++) {
            float4 va = xa[k4], vb = xb[k4];
            accA += va.x * wreg[4 * k4] + va.y * wreg[4 * k4 + 1] +
                    va.z * wreg[4 * k4 + 2] + va.w * wreg[4 * k4 + 3];
            accB += vb.x * wreg[4 * k4] + vb.y * wreg[4 * k4 + 1] +
                    vb.z * wreg[4 * k4 + 2] + vb.w * wreg[4 * k4 + 3];
        }
        h[(size_t)na * HID + c] = accA;
        h[(size_t)nb * HID + c] = accB;
    }
}

// ---- k_linlr_mfma: [xl|xr] = h @ [Wl|Wr] + [bl|br], bf16 out, MFMA ----
__global__ __launch_bounds__(256) void k_linlr_mfma(
    const float* __restrict__ h, const float* __restrict__ Wl,
    const float* __restrict__ bl, const float* __restrict__ Wr,
    const float* __restrict__ br, ushort_t* __restrict__ xl,
    ushort_t* __restrict__ xr) {
    __shared__ ushort_t sW[192 * 104];
    __shared__ float sB[192];
    int t = threadIdx.x;

    for (int idx = t; idx < 192 * 96; idx += 256) {
        int n = idx % 192, k = idx / 192;
        float v = (n < 96) ? Wl[k * 96 + n] : Wr[k * 96 + (n - 96)];
        sW[n * 104 + k] = f2bf(v);
    }
    if (t < 192) sB[t] = (t < 96) ? bl[t] : br[t - 96];
    __syncthreads();

    int wv = t >> 6, lane = t & 63;
    int m0 = blockIdx.x * 64 + wv * 16;
    if (m0 >= N_NODES) return;
    int m = lane & 15, quad = lane >> 4;

    bf16x8 afr[3];
    const float* hrow = h + (size_t)(m0 + m) * HID;
#pragma unroll
    for (int s = 0; s < 3; s++) {
        float4 v0 = *(const float4*)(hrow + s * 32 + quad * 8);
        float4 v1 = *(const float4*)(hrow + s * 32 + quad * 8 + 4);
        bf16x8 a;
        a[0] = (short)f2bf(v0.x); a[1] = (short)f2bf(v0.y);
        a[2] = (short)f2bf(v0.z); a[3] = (short)f2bf(v0.w);
        a[4] = (short)f2bf(v1.x); a[5] = (short)f2bf(v1.y);
        a[6] = (short)f2bf(v1.z); a[7] = (short)f2bf(v1.w);
        afr[s] = a;
    }

#pragma unroll
    for (int nt = 0; nt < 12; nt++) {
        int ch = nt * 16 + m;
        f32x4 acc = {0.f, 0.f, 0.f, 0.f};
#pragma unroll
        for (int s = 0; s < 3; s++) {
            bf16x8 bfr = *(const bf16x8*)(sW + (nt * 16 + m) * 104 + s * 32 + quad * 8);
            acc = __builtin_amdgcn_mfma_f32_16x16x32_bf16(afr[s], bfr, acc, 0, 0, 0);
        }
        float bias = sB[ch];
        ushort_t* dst = (ch < 96) ? (xl + (size_t)(m0 + quad * 4) * HID + ch)
                                  : (xr + (size_t)(m0 + quad * 4) * HID + (ch - 96));
#pragma unroll
        for (int r = 0; r < 4; r++)
            dst[(size_t)r * HID] = f2bf(acc[r] + bias);
    }
}

// ---- k_evagg v3: FUSED ev + aggregation. Same data-flow as v2 (validated:
// ~90MB algorithmic fetch, partL/partR boundary logic passed correctness).
// Register-pressure fixes vs v2 (which spilled: VGPR=120 cap, 140MB scratch
// writes, 18% occupancy):
//  * single-buffered loads (no 2-deep pipeline)      -24 regs
//  * no msrc/mdst arrays (per-batch L1 reloads)      -16 regs
//  * one MFMA live at a time (d consumed per mc)     -20 regs
//  * __launch_bounds__(256,4) pins <=128 VGPR, 16 waves/CU
//  * ea strip-transposed (see k_gather) -> coalesced, -25MB over-fetch
__global__ __launch_bounds__(256, 4) void k_evagg(
    const ushort_t* __restrict__ xlb, const ushort_t* __restrict__ xrb,
    const ushort_t* __restrict__ ea, const int* __restrict__ srcs,
    const int* __restrict__ pdst, const int* __restrict__ rowptr,
    const float* __restrict__ WeL, const float* __restrict__ attL,
    float* __restrict__ accsum, float* __restrict__ accden,
    float* __restrict__ partL, float* __restrict__ partR) {
    int tid = threadIdx.x;
    int base = blockIdx.x * BLKE;
    int nvalid = N_EDGES - base;
    if (nvalid > BLKE) nvalid = BLKE;
    int w = tid >> 6, lane = tid & 63;
    int col = lane & 15, quad = lane >> 4;

    __shared__ float sacc[NMAX][100];   // [0..95] channels, [96..99] den/head
    for (int i = tid; i < NMAX * 100; i += 256) (&sacc[0][0])[i] = 0.f;
    __syncthreads();

    int nlo = pdst[base];

    if (w * 128 < nvalid) {
        int p0 = base + w * 128 + col * 8;

        // wave-invariant A fragments (We^T, remapped channels):
        // lane (quad,col) D rows cover channels quad*24 + mc*4 + r; head = quad.
        bf16x8 afr[6];
#pragma unroll
        for (int mc = 0; mc < 6; mc++) {
            bf16x8 a = {0, 0, 0, 0, 0, 0, 0, 0};
            if (quad < 2) {
                int ch = (col >> 2) * 24 + mc * 4 + (col & 3);
#pragma unroll
                for (int j = 0; j < 8; j++)
                    a[j] = (short)f2bf(WeL[(quad * 8 + j) * HID + ch]);
            }
            afr[mc] = a;
        }
        float attr[6][4];
#pragma unroll
        for (int mc = 0; mc < 6; mc++)
#pragma unroll
            for (int r = 0; r < 4; r++)
                attr[mc][r] = attL[quad * 24 + mc * 4 + r];

        float acc[24];
#pragma unroll
        for (int j = 0; j < 24; j++) acc[j] = 0.f;
        float accd = 0.f;

        int dvprev = pdst[p0];
        uint4 rq0, rq1, rq2;
        {
            const uint4* rp = (const uint4*)(xrb + (size_t)dvprev * HID + quad * 24);
            rq0 = rp[0]; rq1 = rp[1]; rq2 = rp[2];
        }

#pragma unroll
        for (int b = 0; b < 8; b++) {
            int p = p0 + b;
            int sv = srcs[p];
            int dv = pdst[p];
            if (dv != dvprev) {
                // flush + reload xr (node changed within this lane's strip)
                int idx = dvprev - nlo;
                if (idx > NMAX - 1) idx = NMAX - 1;
                float* ap = &sacc[idx][quad * 24];
#pragma unroll
                for (int j = 0; j < 24; j++) atomicAdd(ap + j, acc[j]);
                atomicAdd(&sacc[idx][96 + quad], accd);
#pragma unroll
                for (int j = 0; j < 24; j++) acc[j] = 0.f;
                accd = 0.f;
                const uint4* rp = (const uint4*)(xrb + (size_t)dv * HID + quad * 24);
                rq0 = rp[0]; rq1 = rp[1]; rq2 = rp[2];
                dvprev = dv;
            }

            bf16x8 z8 = {0, 0, 0, 0, 0, 0, 0, 0};
            int slotp = base + w * 128 + b * 16 + col;   // strip-transposed ea
            bf16x8 bfr = (quad < 2)
                ? *(const bf16x8*)(ea + (size_t)slotp * ED + quad * 8) : z8;
            const uint4* xp = (const uint4*)(xlb + (size_t)sv * HID + quad * 24);
            uint4 xq0 = xp[0], xq1 = xp[1], xq2 = xp[2];

            uint_t ux[12] = {xq0.x, xq0.y, xq0.z, xq0.w,
                             xq1.x, xq1.y, xq1.z, xq1.w,
                             xq2.x, xq2.y, xq2.z, xq2.w};
            uint_t ur[12] = {rq0.x, rq0.y, rq0.z, rq0.w,
                             rq1.x, rq1.y, rq1.z, rq1.w,
                             rq2.x, rq2.y, rq2.z, rq2.w};
            float logit = 0.f;
            f32x4 zero4 = {0.f, 0.f, 0.f, 0.f};
#pragma unroll
            for (int mc = 0; mc < 6; mc++) {
                // one MFMA live at a time: consume d before next issue
                f32x4 d = __builtin_amdgcn_mfma_f32_16x16x32_bf16(afr[mc], bfr, zero4, 0, 0, 0);
                uint_t aL = ux[2 * mc], aH = ux[2 * mc + 1];
                uint_t rL = ur[2 * mc], rH = ur[2 * mc + 1];
                float x0 = bf2f((ushort_t)(aL & 0xffff)), x1 = bf2f((ushort_t)(aL >> 16));
                float x2 = bf2f((ushort_t)(aH & 0xffff)), x3 = bf2f((ushort_t)(aH >> 16));
                float r0 = bf2f((ushort_t)(rL & 0xffff)), r1 = bf2f((ushort_t)(rL >> 16));
                float r2 = bf2f((ushort_t)(rH & 0xffff)), r3 = bf2f((ushort_t)(rH >> 16));
                float z0 = x0 + r0 + d[0]; z0 = z0 > 0.f ? z0 : 0.2f * z0;
                float z1 = x1 + r1 + d[1]; z1 = z1 > 0.f ? z1 : 0.2f * z1;
                float z2 = x2 + r2 + d[2]; z2 = z2 > 0.f ? z2 : 0.2f * z2;
                float z3 = x3 + r3 + d[3]; z3 = z3 > 0.f ? z3 : 0.2f * z3;
                logit += z0 * attr[mc][0] + z1 * attr[mc][1] +
                         z2 * attr[mc][2] + z3 * attr[mc][3];
            }
            float ev = __expf(logit);   // head = quad, edge = p0 + b

            // in-register aggregation: this lane's 24 channels, its own ev
#pragma unroll
            for (int mc = 0; mc < 6; mc++) {
                uint_t aL = ux[2 * mc], aH = ux[2 * mc + 1];
                acc[4 * mc + 0] += ev * bf2f((ushort_t)(aL & 0xffff));
                acc[4 * mc + 1] += ev * bf2f((ushort_t)(aL >> 16));
                acc[4 * mc + 2] += ev * bf2f((ushort_t)(aH & 0xffff));
                acc[4 * mc + 3] += ev * bf2f((ushort_t)(aH >> 16));
            }
            accd += ev;
        }
        // final flush
        {
            int idx = dvprev - nlo;
            if (idx > NMAX - 1) idx = NMAX - 1;
            float* ap = &sacc[idx][quad * 24];
#pragma unroll
            for (int j = 0; j < 24; j++) atomicAdd(ap + j, acc[j]);
            atomicAdd(&sacc[idx][96 + quad], accd);
        }
    }
    __syncthreads();

    // -------- parallel writeout: 8 nodes at a time (8 x 32-lane groups) -----
    int nhi = pdst[base + nvalid - 1];
    int grp = tid >> 5, sub = tid & 31;
    int span = nhi - nlo;
    for (int it = 0; it * 8 <= span; ++it) {
        int nd = nlo + it * 8 + grp;
        if (nd <= nhi) {
            int idx = nd - nlo;
            if (idx > NMAX - 1) idx = NMAX - 1;
            int beg = rowptr[nd], end = rowptr[nd + 1];
            bool lb = beg < base;
            bool rb = end > base + nvalid;
            if (sub < 24) {
                float4 v = *(float4*)&sacc[idx][sub * 4];
                float* dst = lb ? (partL + (size_t)blockIdx.x * 100 + sub * 4)
                           : rb ? (partR + (size_t)blockIdx.x * 100 + sub * 4)
                                : (accsum + (size_t)nd * 96 + sub * 4);
                *(float4*)dst = v;
            } else if (sub == 24) {
                float4 dv = *(float4*)&sacc[idx][96];
                float* dst = lb ? (partL + (size_t)blockIdx.x * 100 + 96)
                           : rb ? (partR + (size_t)blockIdx.x * 100 + 96)
                                : (accden + (size_t)nd * 4);
                *(float4*)dst = dv;
            }
        }
    }
}

// ---- k_fin: h = LN(h + acc/den + conv_b). Streaming; resolves the <=2
// cross-block partials per node from rowptr (b0=beg/512, b1=(end-1)/512). ----
__global__ __launch_bounds__(256) void k_fin(
    const float* __restrict__ accsum, const float* __restrict__ accden,
    const float* __restrict__ partL, const float* __restrict__ partR,
    const int* __restrict__ rowptr, const float* __restrict__ convb,
    const float* __restrict__ lng, const float* __restrict__ lnb,
    float* __restrict__ h) {
    int lane = threadIdx.x & 63;
    int slot = lane >> 3, q = lane & 7;
    int node = blockIdx.x * 32 + (threadIdx.x >> 6) * 8 + slot;
    if (node >= N_NODES) return;
    int c0 = q * 12;
    int beg = rowptr[node], end = rowptr[node + 1];

    float a[12];
    float den = 0.f;
    if (beg == end) {
#pragma unroll
        for (int j = 0; j < 12; j++) a[j] = 0.f;
    } else {
        int b0 = beg >> 9, b1 = (end - 1) >> 9;
        if (b0 == b1) {
            const float* ap = accsum + (size_t)node * 96 + c0;
            float4 a0 = *(const float4*)(ap);
            float4 a1 = *(const float4*)(ap + 4);
            float4 a2 = *(const float4*)(ap + 8);
            a[0] = a0.x; a[1] = a0.y; a[2]  = a0.z; a[3]  = a0.w;
            a[4] = a1.x; a[5] = a1.y; a[6]  = a1.z; a[7]  = a1.w;
            a[8] = a2.x; a[9] = a2.y; a[10] = a2.z; a[11] = a2.w;
            den = accden[node * 4 + (q >> 1)];
        } else {
            const float* pR = partR + (size_t)b0 * 100;
            const float* pL = partL + (size_t)b1 * 100;
#pragma unroll
            for (int j = 0; j < 12; j++) a[j] = pR[c0 + j] + pL[c0 + j];
            den = pR[96 + (q >> 1)] + pL[96 + (q >> 1)];
        }
    }

    size_t nb = (size_t)node * HID + c0;
    float inv = 1.f / (den + 1e-16f);
    float4 h0 = *(const float4*)(h + nb);
    float4 h1 = *(const float4*)(h + nb + 4);
    float4 h2 = *(const float4*)(h + nb + 8);
    float vv[12] = {h0.x, h0.y, h0.z, h0.w, h1.x, h1.y, h1.z, h1.w,
                    h2.x, h2.y, h2.z, h2.w};
    float sm = 0.f;
#pragma unroll
    for (int j = 0; j < 12; j++) {
        vv[j] += a[j] * inv + convb[c0 + j];
        sm += vv[j];
    }
    sm += __shfl_xor(sm, 1); sm += __shfl_xor(sm, 2); sm += __shfl_xor(sm, 4);
    float mu = sm * (1.f / 96.f);
    float sv = 0.f;
#pragma unroll
    for (int j = 0; j < 12; j++) {
        vv[j] -= mu;
        sv += vv[j] * vv[j];
    }
    sv += __shfl_xor(sv, 1); sv += __shfl_xor(sv, 2); sv += __shfl_xor(sv, 4);
    float rstd = rsqrtf(sv * (1.f / 96.f) + 1e-5f);
    float o[12];
#pragma unroll
    for (int j = 0; j < 12; j++)
        o[j] = vv[j] * rstd * lng[c0 + j] + lnb[c0 + j];
    *(float4*)(h + nb)     = make_float4(o[0], o[1], o[2], o[3]);
    *(float4*)(h + nb + 4) = make_float4(o[4], o[5], o[6], o[7]);
    *(float4*)(h + nb + 8) = make_float4(o[8], o[9], o[10], o[11]);
}

// ---- k_head_mfma: out = gelu(h@W1+b1)@W2+b2 via MFMA ----
__global__ __launch_bounds__(256) void k_head_mfma(
    const float* __restrict__ h, const float* __restrict__ W1,
    const float* __restrict__ b1, const float* __restrict__ W2,
    const float* __restrict__ b2, float* __restrict__ out) {
    __shared__ ushort_t sW[48 * 104];
    __shared__ float sB1[48];
    __shared__ float sW2[48];
    int t = threadIdx.x;
    for (int idx = t; idx < 48 * 96; idx += 256) {
        int j = idx % 48, k = idx / 48;
        sW[j * 104 + k] = f2bf(W1[k * 48 + j]);
    }
    if (t < 48) { sB1[t] = b1[t]; sW2[t] = W2[t]; }
    __syncthreads();

    int wv = t >> 6, lane = t & 63;
    int m0 = blockIdx.x * 64 + wv * 16;
    if (m0 >= N_NODES) return;
    int col = lane & 15, quad = lane >> 4;

    bf16x8 afr[3];
    const float* hrow = h + (size_t)(m0 + col) * HID;
#pragma unroll
    for (int s = 0; s < 3; s++) {
        float4 v0 = *(const float4*)(hrow + s * 32 + quad * 8);
        float4 v1 = *(const float4*)(hrow + s * 32 + quad * 8 + 4);
        bf16x8 a;
        a[0] = (short)f2bf(v0.x); a[1] = (short)f2bf(v0.y);
        a[2] = (short)f2bf(v0.z); a[3] = (short)f2bf(v0.w);
        a[4] = (short)f2bf(v1.x); a[5] = (short)f2bf(v1.y);
        a[6] = (short)f2bf(v1.z); a[7] = (short)f2bf(v1.w);
        afr[s] = a;
    }

    const float inv_sqrt2 = 0.70710678118654752f;
    float y0 = 0.f, y1 = 0.f, y2 = 0.f, y3 = 0.f;
#pragma unroll
    for (int nt = 0; nt < 3; nt++) {
        f32x4 acc = {0.f, 0.f, 0.f, 0.f};
#pragma unroll
        for (int s = 0; s < 3; s++) {
            bf16x8 bfr = *(const bf16x8*)(sW + (nt * 16 + col) * 104 + s * 32 + quad * 8);
            acc = __builtin_amdgcn_mfma_f32_16x16x32_bf16(afr[s], bfr, acc, 0, 0, 0);
        }
        int ch = nt * 16 + col;
        float bias = sB1[ch], w2 = sW2[ch];
        float v, g;
        v = acc[0] + bias; g = 0.5f * v * (1.f + erff(v * inv_sqrt2)); y0 += g * w2;
        v = acc[1] + bias; g = 0.5f * v * (1.f + erff(v * inv_sqrt2)); y1 += g * w2;
        v = acc[2] + bias; g = 0.5f * v * (1.f + erff(v * inv_sqrt2)); y2 += g * w2;
        v = acc[3] + bias; g = 0.5f * v * (1.f + erff(v * inv_sqrt2)); y3 += g * w2;
    }
    y0 += __shfl_xor(y0, 1); y0 += __shfl_xor(y0, 2);
    y0 += __shfl_xor(y0, 4); y0 += __shfl_xor(y0, 8);
    y1 += __shfl_xor(y1, 1); y1 += __shfl_xor(y1, 2);
    y1 += __shfl_xor(y1, 4); y1 += __shfl_xor(y1, 8);
    y2 += __shfl_xor(y2, 1); y2 += __shfl_xor(y2, 2);
    y2 += __shfl_xor(y2, 4); y2 += __shfl_xor(y2, 8);
    y3 += __shfl_xor(y3, 1); y3 += __shfl_xor(y3, 2);
    y3 += __shfl_xor(y3, 4); y3 += __shfl_xor(y3, 8);
    if (col == 0) {
        float bb = b2[0];
        out[m0 + quad * 4 + 0] = y0 + bb;
        out[m0 + quad * 4 + 1] = y1 + bb;
        out[m0 + quad * 4 + 2] = y2 + bb;
        out[m0 + quad * 4 + 3] = y3 + bb;
    }
}

extern "C" void kernel_launch(void* const* d_in, const int* in_sizes, int n_in,
                              void* d_out, int out_size, void* d_ws, size_t ws_size,
                              hipStream_t stream) {
    const float* x       = (const float*)d_in[0];
    const int*   eidx    = (const int*)  d_in[1];
    const float* eattr   = (const float*)d_in[2];
    const float* proj_w  = (const float*)d_in[3];
    const float* proj_b  = (const float*)d_in[4];
    const float* lin_l_w = (const float*)d_in[5];
    const float* lin_l_b = (const float*)d_in[6];
    const float* lin_r_w = (const float*)d_in[7];
    const float* lin_r_b = (const float*)d_in[8];
    const float* lin_e_w = (const float*)d_in[9];
    const float* att     = (const float*)d_in[10];
    const float* conv_b  = (const float*)d_in[11];
    const float* ln_g    = (const float*)d_in[12];
    const float* ln_b    = (const float*)d_in[13];
    const float* head_w1 = (const float*)d_in[14];
    const float* head_b1 = (const float*)d_in[15];
    const float* head_w2 = (const float*)d_in[16];
    const float* head_b2 = (const float*)d_in[17];
    float* out = (float*)d_out;

    char* p = (char*)d_ws;
    auto alloc = [&](size_t bytes) -> char* {
        char* r = p;
        p += (bytes + 255) & ~size_t(255);
        return r;
    };
    constexpr int NBLK = (N_EDGES + BLKE - 1) / BLKE;   // 1563
    float*    h      = (float*)alloc(sizeof(float) * (size_t)N_NODES * HID);
    ushort_t* xl     = (ushort_t*)alloc(2 * (size_t)N_NODES * HID);
    ushort_t* xr     = (ushort_t*)alloc(2 * (size_t)N_NODES * HID);
    int*      cnt    = (int*)alloc(4 * (size_t)N_NODES);
    int*      rank   = (int*)alloc(4 * (size_t)N_EDGES);
    int*      rowptr = (int*)alloc(4 * (size_t)(N_NODES + 1));
    int*      bsum   = (int*)alloc(4 * 256);
    int2*     csre   = (int2*)alloc(8 * (size_t)N_EDGES);
    int*      srcs   = (int*)alloc(4 * ((size_t)N_EDGES + 256));
    int*      pdst   = (int*)alloc(4 * ((size_t)N_EDGES + 256));
    ushort_t* ea_csr = (ushort_t*)alloc(2 * (size_t)N_EDGES * ED);
    float*    accsum = (float*)alloc(sizeof(float) * (size_t)N_NODES * 96);
    float*    accden = (float*)alloc(sizeof(float) * (size_t)N_NODES * 4);
    float*    partL  = (float*)alloc(sizeof(float) * (size_t)NBLK * 100);
    float*    partR  = (float*)alloc(sizeof(float) * (size_t)NBLK * 100);

    const int* srcA = eidx;
    const int* dstA = eidx + N_EDGES;

    int ebl = (N_EDGES + 255) / 256;   // 3125
    int nbl = (N_NODES + 255) / 256;   // 196

    hipMemsetAsync(cnt, 0, 4 * (size_t)N_NODES, stream);
    k_rank<<<ebl, 256, 0, stream>>>(dstA, cnt, rank);
    k_scan_block<<<nbl, 256, 0, stream>>>(cnt, rowptr, bsum);
    k_scan_bsum<<<1, 256, 0, stream>>>(bsum, nbl);
    k_scan_add<<<nbl, 256, 0, stream>>>(rowptr, bsum);
    k_place<<<ebl, 256, 0, stream>>>(srcA, dstA, rank, rowptr, csre);
    k_gather<<<ebl, 256, 0, stream>>>(csre, dstA, eattr, srcs, pdst, ea_csr);

    k_proj<<<N_NODES / 16, 192, 0, stream>>>(x, proj_w, proj_b, h);
    for (int l = 0; l < NLAYER; l++) {
        k_linlr_mfma<<<(N_NODES + 63) / 64, 256, 0, stream>>>(
            h, lin_l_w + (size_t)l * HID * HID, lin_l_b + (size_t)l * HID,
            lin_r_w + (size_t)l * HID * HID, lin_r_b + (size_t)l * HID, xl, xr);
        k_evagg<<<NBLK, 256, 0, stream>>>(xl, xr, ea_csr, srcs, pdst, rowptr,
                                          lin_e_w + (size_t)l * ED * HID,
                                          att + (size_t)l * HID,
                                          accsum, accden, partL, partR);
        k_fin<<<(N_NODES + 31) / 32, 256, 0, stream>>>(
            accsum, accden, partL, partR, rowptr, conv_b + (size_t)l * HID,
            ln_g + (size_t)l * HID, ln_b + (size_t)l * HID, h);
    }
    k_head_mfma<<<(N_NODES + 63) / 64, 256, 0, stream>>>(h, head_w1, head_b1,
                                                         head_w2, head_b2, out);
}

// Round 7
// 535.343 us; speedup vs baseline: 1.6320x; 1.6320x over previous
//
#include <hip/hip_runtime.h>

constexpr int N_NODES = 50000;
constexpr int N_EDGES = 800000;
constexpr int ND  = 32;
constexpr int ED  = 16;
constexpr int HID = 96;
constexpr int NLAYER = 3;

typedef unsigned short ushort_t;
typedef unsigned int uint_t;
typedef __attribute__((ext_vector_type(8))) short bf16x8;
typedef __attribute__((ext_vector_type(4))) float f32x4;

__device__ __forceinline__ float bf2f(ushort_t u) {
    union { float f; uint_t ui; } c; c.ui = ((uint_t)u) << 16; return c.f;
}
__device__ __forceinline__ ushort_t f2bf(float f) {
    uint_t u = __float_as_uint(f);
    return (ushort_t)((u + 0x7FFFu + ((u >> 16) & 1u)) >> 16);  // RNE
}

// ---------------- CSR build (by dst), once per call ----------------
__global__ void k_rank(const int* __restrict__ dst, int* __restrict__ cnt,
                       int* __restrict__ rank) {
    int e = blockIdx.x * 256 + threadIdx.x;
    if (e >= N_EDGES) return;
    rank[e] = atomicAdd(&cnt[dst[e]], 1);
}

__global__ void k_scan_block(const int* __restrict__ deg, int* __restrict__ rowptr,
                             int* __restrict__ bsum) {
    __shared__ int s[256];
    int i = blockIdx.x * 256 + threadIdx.x;
    int v = (i < N_NODES) ? deg[i] : 0;
    s[threadIdx.x] = v;
    __syncthreads();
    for (int off = 1; off < 256; off <<= 1) {
        int t = (threadIdx.x >= off) ? s[threadIdx.x - off] : 0;
        __syncthreads();
        s[threadIdx.x] += t;
        __syncthreads();
    }
    if (i < N_NODES) rowptr[i] = s[threadIdx.x] - v;
    if (threadIdx.x == 255) bsum[blockIdx.x] = s[255];
}

__global__ void k_scan_bsum(int* __restrict__ bsum, int nb) {
    __shared__ int s[256];
    int t = threadIdx.x;
    int v = (t < nb) ? bsum[t] : 0;
    s[t] = v;
    __syncthreads();
    for (int off = 1; off < 256; off <<= 1) {
        int tv = (t >= off) ? s[t - off] : 0;
        __syncthreads();
        s[t] += tv;
        __syncthreads();
    }
    if (t < nb) bsum[t] = s[t] - v;
}

__global__ void k_scan_add(int* __restrict__ rowptr, const int* __restrict__ bsum) {
    int i = blockIdx.x * 256 + threadIdx.x;
    if (i < N_NODES) rowptr[i] += bsum[blockIdx.x];
    if (i == 0) rowptr[N_NODES] = N_EDGES;
}

__global__ void k_place(const int* __restrict__ src, const int* __restrict__ dst,
                        const int* __restrict__ rank, const int* __restrict__ rowptr,
                        int2* __restrict__ csre) {
    int e = blockIdx.x * 256 + threadIdx.x;
    if (e >= N_EDGES) return;
    int p = rowptr[dst[e]] + rank[e];
    csre[p] = make_int2(src[e], e);
}

__global__ void k_gather(const int2* __restrict__ csre, const int* __restrict__ dstA,
                         const float* __restrict__ eattr, int* __restrict__ srcs,
                         int* __restrict__ pdst, ushort_t* __restrict__ ea) {
    int p = blockIdx.x * 256 + threadIdx.x;
    if (p >= N_EDGES) return;
    int2 se = csre[p];
    int e = se.y;
    srcs[p] = se.x;
    pdst[p] = dstA[e];
    const float4* er = (const float4*)(eattr + (size_t)e * ED);
    float4 v0 = er[0], v1 = er[1], v2 = er[2], v3 = er[3];
    uint4 w0, w1;
    w0.x = (uint_t)f2bf(v0.x) | ((uint_t)f2bf(v0.y) << 16);
    w0.y = (uint_t)f2bf(v0.z) | ((uint_t)f2bf(v0.w) << 16);
    w0.z = (uint_t)f2bf(v1.x) | ((uint_t)f2bf(v1.y) << 16);
    w0.w = (uint_t)f2bf(v1.z) | ((uint_t)f2bf(v1.w) << 16);
    w1.x = (uint_t)f2bf(v2.x) | ((uint_t)f2bf(v2.y) << 16);
    w1.y = (uint_t)f2bf(v2.z) | ((uint_t)f2bf(v2.w) << 16);
    w1.z = (uint_t)f2bf(v3.x) | ((uint_t)f2bf(v3.y) << 16);
    w1.w = (uint_t)f2bf(v3.z) | ((uint_t)f2bf(v3.w) << 16);
    uint4* ew = (uint4*)(ea + (size_t)p * ED);
    ew[0] = w0;
    ew[1] = w1;
}

// ---------------- proj: h = x @ proj_w + proj_b  (K=32) ----------------
__global__ __launch_bounds__(192) void k_proj(const float* __restrict__ x,
                                              const float* __restrict__ pw,
                                              const float* __restrict__ pb,
                                              float* __restrict__ h) {
    int t = threadIdx.x;
    int c = t % 96, half = t / 96;
    float wreg[ND];
#pragma unroll
    for (int k = 0; k < ND; k++) wreg[k] = pw[k * HID + c];
    float b = pb[c];
    int n0 = blockIdx.x * 16 + half * 8;
    for (int i = 0; i < 8; i += 2) {
        int na = n0 + i, nb = na + 1;
        const float4* xa = (const float4*)(x + (size_t)na * ND);
        const float4* xb = (const float4*)(x + (size_t)nb * ND);
        float accA = b, accB = b;
#pragma unroll
        for (int k4 = 0; k4 < ND / 4; k4++) {
            float4 va = xa[k4], vb = xb[k4];
            accA += va.x * wreg[4 * k4] + va.y * wreg[4 * k4 + 1] +
                    va.z * wreg[4 * k4 + 2] + va.w * wreg[4 * k4 + 3];
            accB += vb.x * wreg[4 * k4] + vb.y * wreg[4 * k4 + 1] +
                    vb.z * wreg[4 * k4 + 2] + vb.w * wreg[4 * k4 + 3];
        }
        h[(size_t)na * HID + c] = accA;
        h[(size_t)nb * HID + c] = accB;
    }
}

// ---- k_linlr_mfma: [xl|xr] = h @ [Wl|Wr] + [bl|br], bf16 out, MFMA ----
__global__ __launch_bounds__(256) void k_linlr_mfma(
    const float* __restrict__ h, const float* __restrict__ Wl,
    const float* __restrict__ bl, const float* __restrict__ Wr,
    const float* __restrict__ br, ushort_t* __restrict__ xl,
    ushort_t* __restrict__ xr) {
    __shared__ ushort_t sW[192 * 104];
    __shared__ float sB[192];
    int t = threadIdx.x;

    for (int idx = t; idx < 192 * 96; idx += 256) {
        int n = idx % 192, k = idx / 192;
        float v = (n < 96) ? Wl[k * 96 + n] : Wr[k * 96 + (n - 96)];
        sW[n * 104 + k] = f2bf(v);
    }
    if (t < 192) sB[t] = (t < 96) ? bl[t] : br[t - 96];
    __syncthreads();

    int wv = t >> 6, lane = t & 63;
    int m0 = blockIdx.x * 64 + wv * 16;
    if (m0 >= N_NODES) return;
    int m = lane & 15, quad = lane >> 4;

    bf16x8 afr[3];
    const float* hrow = h + (size_t)(m0 + m) * HID;
#pragma unroll
    for (int s = 0; s < 3; s++) {
        float4 v0 = *(const float4*)(hrow + s * 32 + quad * 8);
        float4 v1 = *(const float4*)(hrow + s * 32 + quad * 8 + 4);
        bf16x8 a;
        a[0] = (short)f2bf(v0.x); a[1] = (short)f2bf(v0.y);
        a[2] = (short)f2bf(v0.z); a[3] = (short)f2bf(v0.w);
        a[4] = (short)f2bf(v1.x); a[5] = (short)f2bf(v1.y);
        a[6] = (short)f2bf(v1.z); a[7] = (short)f2bf(v1.w);
        afr[s] = a;
    }

#pragma unroll
    for (int nt = 0; nt < 12; nt++) {
        int ch = nt * 16 + m;
        f32x4 acc = {0.f, 0.f, 0.f, 0.f};
#pragma unroll
        for (int s = 0; s < 3; s++) {
            bf16x8 bfr = *(const bf16x8*)(sW + (nt * 16 + m) * 104 + s * 32 + quad * 8);
            acc = __builtin_amdgcn_mfma_f32_16x16x32_bf16(afr[s], bfr, acc, 0, 0, 0);
        }
        float bias = sB[ch];
        ushort_t* dst = (ch < 96) ? (xl + (size_t)(m0 + quad * 4) * HID + ch)
                                  : (xr + (size_t)(m0 + quad * 4) * HID + (ch - 96));
#pragma unroll
        for (int r = 0; r < 4; r++)
            dst[(size_t)r * HID] = f2bf(acc[r] + bias);
    }
}

// ---- k_ev: edge-parallel attention weights via MFMA, CSR order.
// DEPTH-3 software pipeline: loads for batch b+2 issued while batch b
// computes. ----
__global__ __launch_bounds__(256) void k_ev(
    const ushort_t* __restrict__ xlb, const ushort_t* __restrict__ xrb,
    const ushort_t* __restrict__ ea, const int* __restrict__ srcs,
    const int* __restrict__ pdst, const float* __restrict__ WeL,
    const float* __restrict__ attL, float* __restrict__ evf) {
    int wid = blockIdx.x * 4 + (threadIdx.x >> 6);
    int lane = threadIdx.x & 63;
    if (wid >= N_EDGES / 128) return;
    int col = lane & 15, quad = lane >> 4;
    int comp = col & 1, base = col >> 1;

    // preload this wave's 128 srcs/pdst values (2 per lane)
    int2 sp = *(const int2*)(srcs + wid * 128 + 2 * lane);
    int2 dp = *(const int2*)(pdst + wid * 128 + 2 * lane);

    // wave-invariant A fragments (We^T, remapped channels)
    bf16x8 afr[6];
#pragma unroll
    for (int mc = 0; mc < 6; mc++) {
        bf16x8 a = {0, 0, 0, 0, 0, 0, 0, 0};
        if (quad < 2) {
            int ch = (col >> 2) * 24 + mc * 4 + (col & 3);
#pragma unroll
            for (int j = 0; j < 8; j++)
                a[j] = (short)f2bf(WeL[(quad * 8 + j) * HID + ch]);
        }
        afr[mc] = a;
    }
    // att for this lane's head (= quad)
    float attr[6][4];
#pragma unroll
    for (int mc = 0; mc < 6; mc++)
#pragma unroll
        for (int r = 0; r < 4; r++)
            attr[mc][r] = attL[quad * 24 + mc * 4 + r];

    // pipeline registers (3 batches in flight)
    bf16x8 bfr[3];
    uint4 xq[3][3], rq[3][3];

    auto getsd = [&](int b, int& sv, int& dv) {
        int sl = b * 8 + base;
        int sx = __shfl(sp.x, sl), sy = __shfl(sp.y, sl);
        int dx = __shfl(dp.x, sl), dy = __shfl(dp.y, sl);
        sv = comp ? sy : sx;
        dv = comp ? dy : dx;
    };
    auto issue = [&](int b, int pp) {
        int sv, dv;
        getsd(b, sv, dv);
        int p = wid * 128 + b * 16 + col;
        bf16x8 z8 = {0, 0, 0, 0, 0, 0, 0, 0};
        bfr[pp] = (quad < 2) ? *(const bf16x8*)(ea + (size_t)p * ED + quad * 8) : z8;
        const uint4* xp = (const uint4*)(xlb + (size_t)sv * HID + quad * 24);
        const uint4* rp = (const uint4*)(xrb + (size_t)dv * HID + quad * 24);
#pragma unroll
        for (int i = 0; i < 3; i++) {
            xq[pp][i] = xp[i];
            rq[pp][i] = rp[i];
        }
    };

    issue(0, 0);
    issue(1, 1);
#pragma unroll
    for (int b = 0; b < 8; b++) {
        int pp = b % 3;
        if (b < 6) issue(b + 2, (b + 2) % 3);

        f32x4 zero4 = {0.f, 0.f, 0.f, 0.f};
        f32x4 d[6];
#pragma unroll
        for (int mc = 0; mc < 6; mc++)
            d[mc] = __builtin_amdgcn_mfma_f32_16x16x32_bf16(afr[mc], bfr[pp], zero4, 0, 0, 0);

        uint_t ux[12] = {xq[pp][0].x, xq[pp][0].y, xq[pp][0].z, xq[pp][0].w,
                         xq[pp][1].x, xq[pp][1].y, xq[pp][1].z, xq[pp][1].w,
                         xq[pp][2].x, xq[pp][2].y, xq[pp][2].z, xq[pp][2].w};
        uint_t ur[12] = {rq[pp][0].x, rq[pp][0].y, rq[pp][0].z, rq[pp][0].w,
                         rq[pp][1].x, rq[pp][1].y, rq[pp][1].z, rq[pp][1].w,
                         rq[pp][2].x, rq[pp][2].y, rq[pp][2].z, rq[pp][2].w};
        float logit = 0.f;
#pragma unroll
        for (int mc = 0; mc < 6; mc++) {
            uint_t aL = ux[2 * mc], aH = ux[2 * mc + 1];
            uint_t rL = ur[2 * mc], rH = ur[2 * mc + 1];
            float x0 = bf2f((ushort_t)(aL & 0xffff)), x1 = bf2f((ushort_t)(aL >> 16));
            float x2 = bf2f((ushort_t)(aH & 0xffff)), x3 = bf2f((ushort_t)(aH >> 16));
            float r0 = bf2f((ushort_t)(rL & 0xffff)), r1 = bf2f((ushort_t)(rL >> 16));
            float r2 = bf2f((ushort_t)(rH & 0xffff)), r3 = bf2f((ushort_t)(rH >> 16));
            float z0 = x0 + r0 + d[mc][0]; z0 = z0 > 0.f ? z0 : 0.2f * z0;
            float z1 = x1 + r1 + d[mc][1]; z1 = z1 > 0.f ? z1 : 0.2f * z1;
            float z2 = x2 + r2 + d[mc][2]; z2 = z2 > 0.f ? z2 : 0.2f * z2;
            float z3 = x3 + r3 + d[mc][3]; z3 = z3 > 0.f ? z3 : 0.2f * z3;
            logit += z0 * attr[mc][0] + z1 * attr[mc][1] +
                     z2 * attr[mc][2] + z3 * attr[mc][3];
        }
        int p = wid * 128 + b * 16 + col;
        evf[4 * p + quad] = __expf(logit);   // coalesced: 64 lanes, 256B run
    }
}

// ---- k_agg: weighted sum + residual + LayerNorm. 8 edge-slots x 8 lanes
// (12 ch/lane, 3x8B loads), serial gather depth = deg/8, 2-stage pipeline. ----
__global__ __launch_bounds__(256) void k_agg(
    const ushort_t* __restrict__ xlb, const float* __restrict__ evf,
    const int* __restrict__ srcs, const int* __restrict__ rowptr,
    const float* __restrict__ convb, const float* __restrict__ lng,
    const float* __restrict__ lnb, float* __restrict__ h) {
    int lane = threadIdx.x & 63;
    int node = blockIdx.x * 4 + (threadIdx.x >> 6);
    int slot = lane >> 3, q = lane & 7;      // 8 slots x 8 channel-lanes
    int c0 = q * 12, head = q >> 1;          // 12 ch/lane; head = c0/24
    int beg = rowptr[node], end = rowptr[node + 1];
    int cnt = (end - beg + 7) >> 3;

    float n[12];
#pragma unroll
    for (int j = 0; j < 12; j++) n[j] = 0.f;
    float den = 0.f;

    if (cnt > 0) {
        int p = beg + slot;
        bool v = p < end;
        int pc = v ? p : beg;
        int src = srcs[pc];
        float evv = evf[4 * pc + head];
        const ushort_t* xp = xlb + (size_t)src * HID + c0;
        uint2 A0 = *(const uint2*)(xp);
        uint2 A1 = *(const uint2*)(xp + 4);
        uint2 A2 = *(const uint2*)(xp + 8);
        for (int it = 0; it < cnt; ++it) {
            int pn = beg + (it + 1) * 8 + slot;
            bool vn = pn < end;
            int pcn = vn ? pn : beg;
            int srcn = srcs[pcn];
            float evn = evf[4 * pcn + head];
            const ushort_t* xpn = xlb + (size_t)srcn * HID + c0;
            uint2 B0 = *(const uint2*)(xpn);
            uint2 B1 = *(const uint2*)(xpn + 4);
            uint2 B2 = *(const uint2*)(xpn + 8);

            float e = v ? evv : 0.f;
            n[0]  += e * bf2f((ushort_t)(A0.x & 0xffff));
            n[1]  += e * bf2f((ushort_t)(A0.x >> 16));
            n[2]  += e * bf2f((ushort_t)(A0.y & 0xffff));
            n[3]  += e * bf2f((ushort_t)(A0.y >> 16));
            n[4]  += e * bf2f((ushort_t)(A1.x & 0xffff));
            n[5]  += e * bf2f((ushort_t)(A1.x >> 16));
            n[6]  += e * bf2f((ushort_t)(A1.y & 0xffff));
            n[7]  += e * bf2f((ushort_t)(A1.y >> 16));
            n[8]  += e * bf2f((ushort_t)(A2.x & 0xffff));
            n[9]  += e * bf2f((ushort_t)(A2.x >> 16));
            n[10] += e * bf2f((ushort_t)(A2.y & 0xffff));
            n[11] += e * bf2f((ushort_t)(A2.y >> 16));
            den += e;

            v = vn; evv = evn;
            A0 = B0; A1 = B1; A2 = B2;
        }
    }
    // combine 8 slots
#pragma unroll
    for (int j = 0; j < 12; j++) {
        n[j] += __shfl_xor(n[j], 8);
        n[j] += __shfl_xor(n[j], 16);
        n[j] += __shfl_xor(n[j], 32);
    }
    den += __shfl_xor(den, 8);
    den += __shfl_xor(den, 16);
    den += __shfl_xor(den, 32);

    size_t nb = (size_t)node * HID + c0;
    float inv = 1.f / (den + 1e-16f);
    float4 h0 = *(const float4*)(h + nb);
    float4 h1 = *(const float4*)(h + nb + 4);
    float4 h2 = *(const float4*)(h + nb + 8);
    float vv[12] = {h0.x, h0.y, h0.z, h0.w, h1.x, h1.y, h1.z, h1.w,
                    h2.x, h2.y, h2.z, h2.w};
    float sm = 0.f;
#pragma unroll
    for (int j = 0; j < 12; j++) {
        vv[j] += n[j] * inv + convb[c0 + j];
        sm += vv[j];
    }
    sm += __shfl_xor(sm, 1); sm += __shfl_xor(sm, 2); sm += __shfl_xor(sm, 4);
    float mu = sm * (1.f / 96.f);
    float sv = 0.f;
#pragma unroll
    for (int j = 0; j < 12; j++) {
        vv[j] -= mu;
        sv += vv[j] * vv[j];
    }
    sv += __shfl_xor(sv, 1); sv += __shfl_xor(sv, 2); sv += __shfl_xor(sv, 4);
    float rstd = rsqrtf(sv * (1.f / 96.f) + 1e-5f);
    if (slot == 0) {
        float o[12];
#pragma unroll
        for (int j = 0; j < 12; j++)
            o[j] = vv[j] * rstd * lng[c0 + j] + lnb[c0 + j];
        *(float4*)(h + nb)     = make_float4(o[0], o[1], o[2], o[3]);
        *(float4*)(h + nb + 4) = make_float4(o[4], o[5], o[6], o[7]);
        *(float4*)(h + nb + 8) = make_float4(o[8], o[9], o[10], o[11]);
    }
}

// ---- k_head_mfma: out = gelu(h@W1+b1)@W2+b2 via MFMA ----
__global__ __launch_bounds__(256) void k_head_mfma(
    const float* __restrict__ h, const float* __restrict__ W1,
    const float* __restrict__ b1, const float* __restrict__ W2,
    const float* __restrict__ b2, float* __restrict__ out) {
    __shared__ ushort_t sW[48 * 104];
    __shared__ float sB1[48];
    __shared__ float sW2[48];
    int t = threadIdx.x;
    for (int idx = t; idx < 48 * 96; idx += 256) {
        int j = idx % 48, k = idx / 48;
        sW[j * 104 + k] = f2bf(W1[k * 48 + j]);
    }
    if (t < 48) { sB1[t] = b1[t]; sW2[t] = W2[t]; }
    __syncthreads();

    int wv = t >> 6, lane = t & 63;
    int m0 = blockIdx.x * 64 + wv * 16;
    if (m0 >= N_NODES) return;
    int col = lane & 15, quad = lane >> 4;

    bf16x8 afr[3];
    const float* hrow = h + (size_t)(m0 + col) * HID;
#pragma unroll
    for (int s = 0; s < 3; s++) {
        float4 v0 = *(const float4*)(hrow + s * 32 + quad * 8);
        float4 v1 = *(const float4*)(hrow + s * 32 + quad * 8 + 4);
        bf16x8 a;
        a[0] = (short)f2bf(v0.x); a[1] = (short)f2bf(v0.y);
        a[2] = (short)f2bf(v0.z); a[3] = (short)f2bf(v0.w);
        a[4] = (short)f2bf(v1.x); a[5] = (short)f2bf(v1.y);
        a[6] = (short)f2bf(v1.z); a[7] = (short)f2bf(v1.w);
        afr[s] = a;
    }

    const float inv_sqrt2 = 0.70710678118654752f;
    float y0 = 0.f, y1 = 0.f, y2 = 0.f, y3 = 0.f;
#pragma unroll
    for (int nt = 0; nt < 3; nt++) {
        f32x4 acc = {0.f, 0.f, 0.f, 0.f};
#pragma unroll
        for (int s = 0; s < 3; s++) {
            bf16x8 bfr = *(const bf16x8*)(sW + (nt * 16 + col) * 104 + s * 32 + quad * 8);
            acc = __builtin_amdgcn_mfma_f32_16x16x32_bf16(afr[s], bfr, acc, 0, 0, 0);
        }
        int ch = nt * 16 + col;
        float bias = sB1[ch], w2 = sW2[ch];
        float v, g;
        v = acc[0] + bias; g = 0.5f * v * (1.f + erff(v * inv_sqrt2)); y0 += g * w2;
        v = acc[1] + bias; g = 0.5f * v * (1.f + erff(v * inv_sqrt2)); y1 += g * w2;
        v = acc[2] + bias; g = 0.5f * v * (1.f + erff(v * inv_sqrt2)); y2 += g * w2;
        v = acc[3] + bias; g = 0.5f * v * (1.f + erff(v * inv_sqrt2)); y3 += g * w2;
    }
    y0 += __shfl_xor(y0, 1); y0 += __shfl_xor(y0, 2);
    y0 += __shfl_xor(y0, 4); y0 += __shfl_xor(y0, 8);
    y1 += __shfl_xor(y1, 1); y1 += __shfl_xor(y1, 2);
    y1 += __shfl_xor(y1, 4); y1 += __shfl_xor(y1, 8);
    y2 += __shfl_xor(y2, 1); y2 += __shfl_xor(y2, 2);
    y2 += __shfl_xor(y2, 4); y2 += __shfl_xor(y2, 8);
    y3 += __shfl_xor(y3, 1); y3 += __shfl_xor(y3, 2);
    y3 += __shfl_xor(y3, 4); y3 += __shfl_xor(y3, 8);
    if (col == 0) {
        float bb = b2[0];
        out[m0 + quad * 4 + 0] = y0 + bb;
        out[m0 + quad * 4 + 1] = y1 + bb;
        out[m0 + quad * 4 + 2] = y2 + bb;
        out[m0 + quad * 4 + 3] = y3 + bb;
    }
}

extern "C" void kernel_launch(void* const* d_in, const int* in_sizes, int n_in,
                              void* d_out, int out_size, void* d_ws, size_t ws_size,
                              hipStream_t stream) {
    const float* x       = (const float*)d_in[0];
    const int*   eidx    = (const int*)  d_in[1];
    const float* eattr   = (const float*)d_in[2];
    const float* proj_w  = (const float*)d_in[3];
    const float* proj_b  = (const float*)d_in[4];
    const float* lin_l_w = (const float*)d_in[5];
    const float* lin_l_b = (const float*)d_in[6];
    const float* lin_r_w = (const float*)d_in[7];
    const float* lin_r_b = (const float*)d_in[8];
    const float* lin_e_w = (const float*)d_in[9];
    const float* att     = (const float*)d_in[10];
    const float* conv_b  = (const float*)d_in[11];
    const float* ln_g    = (const float*)d_in[12];
    const float* ln_b    = (const float*)d_in[13];
    const float* head_w1 = (const float*)d_in[14];
    const float* head_b1 = (const float*)d_in[15];
    const float* head_w2 = (const float*)d_in[16];
    const float* head_b2 = (const float*)d_in[17];
    float* out = (float*)d_out;

    char* p = (char*)d_ws;
    auto alloc = [&](size_t bytes) -> char* {
        char* r = p;
        p += (bytes + 255) & ~size_t(255);
        return r;
    };
    float*    h      = (float*)alloc(sizeof(float) * (size_t)N_NODES * HID);
    ushort_t* xl     = (ushort_t*)alloc(2 * (size_t)N_NODES * HID);
    ushort_t* xr     = (ushort_t*)alloc(2 * (size_t)N_NODES * HID);
    int*      cnt    = (int*)alloc(4 * (size_t)N_NODES);
    int*      rank   = (int*)alloc(4 * (size_t)N_EDGES);
    int*      rowptr = (int*)alloc(4 * (size_t)(N_NODES + 1));
    int*      bsum   = (int*)alloc(4 * 256);
    int2*     csre   = (int2*)alloc(8 * (size_t)N_EDGES);
    int*      srcs   = (int*)alloc(4 * ((size_t)N_EDGES + 256));
    int*      pdst   = (int*)alloc(4 * ((size_t)N_EDGES + 256));
    ushort_t* ea_csr = (ushort_t*)alloc(2 * (size_t)N_EDGES * ED);
    float*    ev     = (float*)alloc(16 * (size_t)N_EDGES);

    const int* srcA = eidx;
    const int* dstA = eidx + N_EDGES;

    int ebl = (N_EDGES + 255) / 256;   // 3125
    int nbl = (N_NODES + 255) / 256;   // 196

    hipMemsetAsync(cnt, 0, 4 * (size_t)N_NODES, stream);
    k_rank<<<ebl, 256, 0, stream>>>(dstA, cnt, rank);
    k_scan_block<<<nbl, 256, 0, stream>>>(cnt, rowptr, bsum);
    k_scan_bsum<<<1, 256, 0, stream>>>(bsum, nbl);
    k_scan_add<<<nbl, 256, 0, stream>>>(rowptr, bsum);
    k_place<<<ebl, 256, 0, stream>>>(srcA, dstA, rank, rowptr, csre);
    k_gather<<<ebl, 256, 0, stream>>>(csre, dstA, eattr, srcs, pdst, ea_csr);

    k_proj<<<N_NODES / 16, 192, 0, stream>>>(x, proj_w, proj_b, h);
    for (int l = 0; l < NLAYER; l++) {
        k_linlr_mfma<<<(N_NODES + 63) / 64, 256, 0, stream>>>(
            h, lin_l_w + (size_t)l * HID * HID, lin_l_b + (size_t)l * HID,
            lin_r_w + (size_t)l * HID * HID, lin_r_b + (size_t)l * HID, xl, xr);
        k_ev<<<1563, 256, 0, stream>>>(xl, xr, ea_csr, srcs, pdst,
                                       lin_e_w + (size_t)l * ED * HID,
                                       att + (size_t)l * HID, ev);
        k_agg<<<N_NODES / 4, 256, 0, stream>>>(
            xl, ev, srcs, rowptr, conv_b + (size_t)l * HID,
            ln_g + (size_t)l * HID, ln_b + (size_t)l * HID, h);
    }
    k_head_mfma<<<(N_NODES + 63) / 64, 256, 0, stream>>>(h, head_w1, head_b1,
                                                         head_w2, head_b2, out);
}